// Round 15
// baseline (884.059 us; speedup 1.0000x reference)
//
#include <hip/hip_runtime.h>
#include <hip/hip_bf16.h>
#include <stdint.h>

// ---------------------------------------------------------------------------
// Problem geometry
//   x (4,400,128) -> conv1d(200->512,k3,p1,relu) -> conv1d(512->128,k3,p1,relu) = h
//   x4 = sigmoid(0.01*conv1d(h, w3(3,128,1))) -> outputs xc(ch2), xb_start(ch0), xb_end(ch1)
//   cm = einsum('bct,tm->bcm', h, mask) ; conv3d(w3d, stride 32) + b3d, relu
//     == relu(b3d[o] + sum_{s,t} mask[t,s,i,j] * H2[b,o,s,t])   (<=6 taps/(s,i,j))
//   then 1x1(512->128,relu) [MFMA], 3x3(128->64,relu) [MFMA], 3x3(64->64,relu)
//   [MFMA, fused with final 1x1 64->4 sigmoid via cross-lane reduce]
//   outputs (float32): xc,xb_start,xb_end (3*512) | iou (4,2,128,128) | prop_start | prop_end
//
// cm stored TRANSPOSED: cm2[ij][bo]. k_bm (round-13 proven inner loop): 64-thr
// single-wave blocks, bo-quad per thread, per-column tap loop, LDS broadcast;
// split into two y-half dispatches for profiling visibility (same total work).
// MFMA fragment mapping (HW-validated by round-10 conva): A row=lane&15,
// k=(lane>>4)*8+e; B col=lane&15; D col=lane&15, row=(lane>>4)*4+reg.
// ---------------------------------------------------------------------------

typedef unsigned int uint32;
typedef __attribute__((ext_vector_type(8))) short bf16x8;
typedef __attribute__((ext_vector_type(4))) float f32x4;

__device__ __forceinline__ float bf2f(ushort u) {
    return __uint_as_float(((uint32)u) << 16);
}
__device__ __forceinline__ ushort f2bf(float f) {
    uint32 x = __float_as_uint(f);
    uint32 r = (x + 0x7FFFu + ((x >> 16) & 1u)) >> 16;
    return (ushort)r;
}
__device__ __forceinline__ float sigmoidf(float x) {
    return 1.0f / (1.0f + __expf(-x));
}

// ---------------------------------------------------------------------------
// k_prep1: conv1d weight transposes (before conv1d).
//   sec A (blocks 0..1199):   w1 (512,200,3) -> w1T[(c*3+k)][512]
//   sec B (blocks 1200..1967): w2 (128,512,3) -> w2T[(c*3+k)][128]
// ---------------------------------------------------------------------------
__global__ __launch_bounds__(256) void k_prep1(
    const float* __restrict__ w1, float* __restrict__ w1T,
    const float* __restrict__ w2, float* __restrict__ w2T)
{
    int bid = blockIdx.x;
    if (bid < 1200) {
        int n = bid * 256 + threadIdx.x;
        if (n < 600 * 512) {
            int o = n % 512, rem = n / 512;
            w1T[n] = w1[(size_t)o * 600 + rem];
        }
    } else {
        int n = (bid - 1200) * 256 + threadIdx.x;
        if (n < 1536 * 128) {
            int o = n % 128, rem = n / 128;
            w2T[n] = w2[(size_t)o * 1536 + rem];
        }
    }
}

// ---------------------------------------------------------------------------
// k_prep2 (after e2; ewf zone dead):
//   sec A (0..511):    w3d (512,128,32) -> w3dT[s][o][c], LDS-tiled (o = bid)
//   sec B (512..799):  wb -> wbB bf16 [kk][64][128]
//   sec C (800..943):  wc -> wcB bf16 [kk][64][64]
//   sec D (944..1199): wa -> waB bf16 row-major
// ---------------------------------------------------------------------------
__global__ __launch_bounds__(256) void k_prep2(
    const float* __restrict__ w3d, float* __restrict__ w3dT,
    const float* __restrict__ wb, ushort* __restrict__ wbB,
    const float* __restrict__ wc, ushort* __restrict__ wcB,
    const float* __restrict__ wa, ushort* __restrict__ waB)
{
    int bid = blockIdx.x;
    if (bid < 512) {
        __shared__ float lt[128 * 33];
        int o = bid;
        for (int n = threadIdx.x; n < 4096; n += 256) {
            // n = c*32 + s (coalesced read)
            lt[(n >> 5) * 33 + (n & 31)] = w3d[(size_t)o * 4096 + n];
        }
        __syncthreads();
        for (int n = threadIdx.x; n < 4096; n += 256) {
            // n = s*128 + c (coalesced write)
            int s = n >> 7, c = n & 127;
            w3dT[((size_t)(s * 512 + o)) * 128 + c] = lt[c * 33 + s];
        }
    } else if (bid < 800) {
        int n = (bid - 512) * 256 + threadIdx.x;
        if (n < 64 * 128 * 9) {
            int kk = n % 9, rest = n / 9;
            int cin = rest & 127, cout = rest >> 7;
            wbB[((size_t)(kk * 64 + cout)) * 128 + cin] = f2bf(wb[n]);
        }
    } else if (bid < 944) {
        int n = (bid - 800) * 256 + threadIdx.x;
        if (n < 64 * 64 * 9) {
            int kk = n % 9, rest = n / 9;
            int cin = rest & 63, cout = rest >> 6;
            wcB[((size_t)(kk * 64 + cout)) * 64 + cin] = f2bf(wc[n]);
        }
    } else {
        int n = (bid - 944) * 256 + threadIdx.x;
        waB[n] = f2bf(wa[n]);
    }
}

// ---------------------------------------------------------------------------
// conv1d (k=3, pad=1, relu). Block: 16 out-channels x 128 t. Grid (COUT/16, B).
// ---------------------------------------------------------------------------
__global__ __launch_bounds__(256) void k_conv1d_relu(
    const float* __restrict__ in, const float* __restrict__ wT,
    const float* __restrict__ bias, float* __restrict__ out,
    int CIN, int in_batch_stride, int COUT)
{
    __shared__ float lx[64 * 132];   // [c][0..127 data, 128 = zero pad]
    __shared__ float lws[64 * 48];   // [c][k][16 o]
    int b  = blockIdx.y;
    int ooL = threadIdx.x >> 4;
    int o  = blockIdx.x * 16 + ooL;
    int tg = threadIdx.x & 15;
    int t0 = tg * 8;

    float acc[8];
#pragma unroll
    for (int k = 0; k < 8; ++k) acc[k] = 0.0f;

    for (int c0 = 0; c0 < CIN; c0 += 64) {
        int nc = CIN - c0; if (nc > 64) nc = 64;
        __syncthreads();
        for (int n = threadIdx.x; n < nc * 32; n += 256) {
            int cl = n >> 5, q = n & 31;
            float4 v = *(const float4*)(in + ((size_t)(b * in_batch_stride + c0 + cl)) * 128 + q * 4);
            *(float4*)(&lx[cl * 132 + q * 4]) = v;
        }
        for (int cl = threadIdx.x; cl < nc; cl += 256) lx[cl * 132 + 128] = 0.0f;
        for (int n = threadIdx.x; n < nc * 48; n += 256) {
            int cl = n / 48, r = n - cl * 48;       // r = k*16 + oo
            lws[n] = wT[((size_t)(c0 + cl) * 3 + (r >> 4)) * COUT + blockIdx.x * 16 + (r & 15)];
        }
        __syncthreads();

        for (int cl = 0; cl < nc; ++cl) {
            const float* wrow = &lws[cl * 48 + ooL];
            float w0 = wrow[0], w1 = wrow[16], w2 = wrow[32];
            const float* row = &lx[cl * 132];
            float xv[10];
            if (t0 == 0) {
                xv[0] = 0.0f;
#pragma unroll
                for (int k = 1; k < 10; ++k) xv[k] = row[k - 1];
            } else {
#pragma unroll
                for (int k = 0; k < 10; ++k) xv[k] = row[t0 - 1 + k];
            }
#pragma unroll
            for (int k = 0; k < 8; ++k)
                acc[k] += w0 * xv[k] + w1 * xv[k + 1] + w2 * xv[k + 2];
        }
    }
    float bo = bias[o];
#pragma unroll
    for (int k = 0; k < 8; ++k) {
        float v = acc[k] + bo;
        out[((size_t)(b * COUT + o)) * 128 + t0 + k] = v > 0.0f ? v : 0.0f;
    }
}

// ---------------------------------------------------------------------------
// x4 head -> d_out[0:1536] floats: (xc=ch2 | xb_start=ch0 | xb_end=ch1)
// ---------------------------------------------------------------------------
__global__ void k_x4(const float* __restrict__ h, const float* __restrict__ w3,
                     const float* __restrict__ b3, float* __restrict__ outp)
{
    int tid = threadIdx.x;
    int b = tid >> 7, t = tid & 127;
    float a0 = 0.f, a1 = 0.f, a2 = 0.f;
    for (int c = 0; c < 128; ++c) {
        float hv = h[((size_t)(b * 128 + c)) * 128 + t];
        a0 += w3[c] * hv;
        a1 += w3[128 + c] * hv;
        a2 += w3[256 + c] * hv;
    }
    float s0 = sigmoidf(0.01f * (a0 + b3[0]));
    float s1 = sigmoidf(0.01f * (a1 + b3[1]));
    float s2 = sigmoidf(0.01f * (a2 + b3[2]));
    int bt = b * 128 + t;
    outp[bt]        = s2;   // xc
    outp[512 + bt]  = s0;   // xb_start
    outp[1024 + bt] = s1;   // xb_end
}

// ---------------------------------------------------------------------------
// H2t[(s*128+t)*2048 + b*512+o] = bf16( sum_c w3dT[s][o][c]*h[b,c,t] )
// ---------------------------------------------------------------------------
__global__ __launch_bounds__(256) void k_h2(
    const float* __restrict__ h, const float* __restrict__ w3dT,
    ushort* __restrict__ h2t)
{
    __shared__ float lw[64 * 132];     // [o][c] stride 132
    __shared__ float lhs[32 * 132];    // [c_local][t] ; reused as out stage
    int ot = blockIdx.x, s = blockIdx.y, b = blockIdx.z;
    int o0 = ot * 64;

    for (int n = threadIdx.x; n < 2048; n += 256) {
        int o = n >> 5, q = n & 31;
        *(float4*)(&lw[o * 132 + q * 4]) =
            *(const float4*)(w3dT + ((size_t)(s * 512 + o0 + o)) * 128 + q * 4);
    }

    int og = threadIdx.x >> 4, tg = threadIdx.x & 15;
    int o0t = og * 4, t0 = tg * 8;
    float acc[4][8];
#pragma unroll
    for (int oo = 0; oo < 4; ++oo)
#pragma unroll
        for (int k = 0; k < 8; ++k) acc[oo][k] = 0.0f;

    for (int c0 = 0; c0 < 128; c0 += 32) {
        __syncthreads();
        for (int n = threadIdx.x; n < 1024; n += 256) {
            int cl = n >> 5, q = n & 31;
            *(float4*)(&lhs[cl * 132 + q * 4]) =
                *(const float4*)(h + ((size_t)(b * 128 + c0 + cl)) * 128 + q * 4);
        }
        __syncthreads();
        for (int cl = 0; cl < 32; ++cl) {
            float hv[8];
#pragma unroll
            for (int k = 0; k < 8; ++k) hv[k] = lhs[cl * 132 + t0 + k];
#pragma unroll
            for (int oo = 0; oo < 4; ++oo) {
                float wv = lw[(o0t + oo) * 132 + c0 + cl];
#pragma unroll
                for (int k = 0; k < 8; ++k) acc[oo][k] += wv * hv[k];
            }
        }
    }
    __syncthreads();
    ushort* lout = (ushort*)lhs;       // [t*64 + o]
#pragma unroll
    for (int oo = 0; oo < 4; ++oo)
#pragma unroll
        for (int k = 0; k < 8; ++k)
            lout[(t0 + k) * 64 + o0t + oo] = f2bf(acc[oo][k]);
    __syncthreads();
    for (int n = threadIdx.x; n < 8192; n += 256) {
        int t = n >> 6, o = n & 63;
        h2t[(size_t)(s * 128 + t) * 2048 + b * 512 + o0 + o] = lout[n];
    }
}

// ---------------------------------------------------------------------------
// E1: per mask column m=(s,i,j), collect nonzero (t,w) taps (<=6 exist, cap 8).
// ---------------------------------------------------------------------------
__global__ __launch_bounds__(256) void k_e1(
    const float* __restrict__ mask, uint32* __restrict__ ecnt,
    uint8_t* __restrict__ et, float* __restrict__ ew)
{
    uint32 m = blockIdx.x * 256 + threadIdx.x;
    int cnt = 0;
    for (int t = 0; t < 128; ++t) {
        float w = mask[(size_t)t * 524288 + m];
        if (w != 0.0f) {
            if (cnt < 8) {
                et[(size_t)m * 8 + cnt] = (uint8_t)t;
                ew[(size_t)m * 8 + cnt] = w;
            }
            cnt++;
        }
    }
    ecnt[m] = (uint32)(cnt < 8 ? cnt : 8);
}

// ---------------------------------------------------------------------------
// E2: merge per (i,j): taps over all 32 s -> packed {w_bits, byte_off} (<=192).
// ---------------------------------------------------------------------------
__global__ void k_e2(const uint32* __restrict__ ecnt, const uint8_t* __restrict__ et,
                     const float* __restrict__ ew, uint32* __restrict__ cntij,
                     int2* __restrict__ taps)
{
    int lane = threadIdx.x & 31;
    int col = blockIdx.x * 2 + (threadIdx.x >> 5);
    uint32 m = (uint32)lane * 16384u + (uint32)col;
    int c = (int)ecnt[m];
    int v = c;
    for (int d = 1; d < 32; d <<= 1) {
        int t = __shfl_up(v, d, 32);
        if (lane >= d) v += t;
    }
    int off = v - c;
    if (lane == 31) cntij[col] = (uint32)v;
    for (int k = 0; k < c; ++k) {
        int2 r;
        r.x = __float_as_int(ew[(size_t)m * 8 + k]);
        r.y = ((lane << 7) + (int)et[(size_t)m * 8 + k]) << 12;   // st * 4096 bytes
        taps[(size_t)col * 192 + off + k] = r;
    }
}

// ---------------------------------------------------------------------------
// k_bm (round-13 proven inner loop): cm2[ij, bo] = relu(b3d + sum w*H2t[st,bo])
// 64-thr single-wave blocks; bo-quad per thread (dwordx2 = 4 bf16 = 4 MACs).
// Per-column tap loop (unroll 8); taps broadcast from 6 KB LDS. Grid
// (x=boT 8 -> XCD-pinned 2MB h2t slice, y = 1024 half) x2 dispatches.
// ---------------------------------------------------------------------------
__global__ __launch_bounds__(64) void k_bm(
    const ushort* __restrict__ h2t, const int2* __restrict__ taps,
    const uint32* __restrict__ cntij, const float* __restrict__ b3d,
    ushort* __restrict__ cm2, int yoff)
{
    __shared__ int2 tl[4 * 192];        // 6,144 B
    int boT = blockIdx.x;
    int y = blockIdx.y + yoff;
    int i = y >> 4, oc = y & 15;
    int tid = threadIdx.x;
    int bo0 = boT * 256 + tid * 4;
    const char* hb = (const char*)h2t + (size_t)bo0 * 2;
    float4 bias = *(const float4*)(b3d + (bo0 & 511));

    for (int jc = 0; jc < 2; ++jc) {
        int j0 = oc * 8 + jc * 4;
        int ij0 = i * 128 + j0;
        int cnts[4];
#pragma unroll
        for (int c = 0; c < 4; ++c) cnts[c] = (int)cntij[ij0 + c];
        __syncthreads();   // previous chunk's readers done before tl overwrite
        for (int n = tid; n < 768; n += 64) {
            int c = n / 192, k = n - c * 192;
            if (k < cnts[c]) tl[n] = taps[(size_t)(ij0 + c) * 192 + k];
        }
        __syncthreads();
#pragma unroll 1
        for (int c = 0; c < 4; ++c) {
            int cnt = cnts[c];
            const int2* tp = &tl[c * 192];
            float a0 = 0.f, a1 = 0.f, a2 = 0.f, a3 = 0.f;
#pragma unroll 8
            for (int k = 0; k < cnt; ++k) {
                int2 r = tp[k];
                uint2 hv = *(const uint2*)(hb + (uint32)r.y);
                float w = __int_as_float(r.x);
                a0 += w * __uint_as_float(hv.x << 16);
                a1 += w * __uint_as_float(hv.x & 0xffff0000u);
                a2 += w * __uint_as_float(hv.y << 16);
                a3 += w * __uint_as_float(hv.y & 0xffff0000u);
            }
            float v0 = fmaxf(a0 + bias.x, 0.f);
            float v1 = fmaxf(a1 + bias.y, 0.f);
            float v2 = fmaxf(a2 + bias.z, 0.f);
            float v3 = fmaxf(a3 + bias.w, 0.f);
            uint64_t pr = (uint64_t)((uint32)f2bf(v0) | ((uint32)f2bf(v1) << 16))
                        | ((uint64_t)((uint32)f2bf(v2) | ((uint32)f2bf(v3) << 16)) << 32);
            __builtin_nontemporal_store(pr, (uint64_t*)(cm2 + (size_t)(ij0 + c) * 2048 + bo0));
        }
    }
}

// ---------------------------------------------------------------------------
// conv-a via MFMA: p1b[b][ij][c] = bf16(relu(ba[c] + sum_o waB[c,o]*cm2[ij,b*512+o]))
// ---------------------------------------------------------------------------
__global__ __launch_bounds__(256) void k_convaM(
    const ushort* __restrict__ cm2, const ushort* __restrict__ waB,
    const float* __restrict__ ba, ushort* __restrict__ p1b)
{
    int b = blockIdx.y;
    int wv = threadIdx.x >> 6, l = threadIdx.x & 63;
    int ij0 = blockIdx.x * 64 + wv * 16;
    int l15 = l & 15, g = l >> 4;

    f32x4 acc[8];
#pragma unroll
    for (int m = 0; m < 8; ++m) acc[m] = (f32x4){0.f, 0.f, 0.f, 0.f};

    const ushort* bbase = cm2 + (size_t)(ij0 + l15) * 2048 + b * 512 + g * 8;
    const ushort* abase = waB + (size_t)l15 * 512 + g * 8;

#pragma unroll 2
    for (int o0 = 0; o0 < 512; o0 += 32) {
        bf16x8 bv = *(const bf16x8*)(bbase + o0);
#pragma unroll
        for (int m = 0; m < 8; ++m) {
            bf16x8 av = *(const bf16x8*)(abase + (size_t)(m * 16) * 512 + o0);
            acc[m] = __builtin_amdgcn_mfma_f32_16x16x32_bf16(av, bv, acc[m], 0, 0, 0);
        }
    }

    int ij = ij0 + l15;
    ushort* ob = p1b + ((size_t)(b * 16384 + ij)) * 128;
#pragma unroll
    for (int m = 0; m < 8; ++m) {
        int c = m * 16 + g * 4;
        float v0 = fmaxf(acc[m][0] + ba[c], 0.f);
        float v1 = fmaxf(acc[m][1] + ba[c + 1], 0.f);
        float v2 = fmaxf(acc[m][2] + ba[c + 2], 0.f);
        float v3 = fmaxf(acc[m][3] + ba[c + 3], 0.f);
        uint2 pk;
        pk.x = (uint32)f2bf(v0) | ((uint32)f2bf(v1) << 16);
        pk.y = (uint32)f2bf(v2) | ((uint32)f2bf(v3) << 16);
        *(uint2*)(ob + c) = pk;
    }
}

// ---------------------------------------------------------------------------
// 3x3 conv via MFMA (implicit GEMM over 9 shifted taps).
// inB: [b][ij][CIN] bf16. wB: [kk][64][CIN] bf16. Wave owns 64c x 16ij.
// MODE 1: bf16 out [b][ij][64]. MODE 2: fused final 1x1(64->4)+sigmoid.
// ---------------------------------------------------------------------------
template <int CIN, int MODE>
__global__ __launch_bounds__(256) void k_conv3x3M(
    const ushort* __restrict__ inB, const ushort* __restrict__ wB,
    const float* __restrict__ bias, void* __restrict__ outp,
    const float* __restrict__ wd, const float* __restrict__ bd)
{
    int b = blockIdx.y;
    int wv = threadIdx.x >> 6, l = threadIdx.x & 63;
    int l15 = l & 15, g = l >> 4;
    int tile = blockIdx.x;                 // 0..255
    int i = tile >> 1;
    int j = (tile & 1) * 64 + wv * 16 + l15;
    const ushort* inb = inB + (size_t)b * 16384 * CIN;

    f32x4 acc[4];
#pragma unroll
    for (int m = 0; m < 4; ++m) acc[m] = (f32x4){0.f, 0.f, 0.f, 0.f};

#pragma unroll
    for (int ky = 0; ky < 3; ++ky) {
        int ii = i + ky - 1;
        if (ii < 0 || ii >= 128) continue;      // uniform per block
#pragma unroll
        for (int kx = 0; kx < 3; ++kx) {
            int jv = j + kx - 1;
            bool ok = (jv >= 0) && (jv < 128);  // per-lane
            const ushort* bp = inb + (size_t)(ii * 128 + jv) * CIN + g * 8;
            const ushort* ap = wB + (size_t)((ky * 3 + kx) * 64 + l15) * CIN + g * 8;
#pragma unroll
            for (int o0 = 0; o0 < CIN; o0 += 32) {
                bf16x8 bv;
                if (ok) bv = *(const bf16x8*)(bp + o0);
                else    bv = (bf16x8){0, 0, 0, 0, 0, 0, 0, 0};
#pragma unroll
                for (int m = 0; m < 4; ++m) {
                    bf16x8 av = *(const bf16x8*)(ap + (size_t)(m * 16) * CIN + o0);
                    acc[m] = __builtin_amdgcn_mfma_f32_16x16x32_bf16(av, bv, acc[m], 0, 0, 0);
                }
            }
        }
    }

    int ij = i * 128 + j;
    if (MODE == 1) {
        ushort* ob = (ushort*)outp + ((size_t)(b * 16384 + ij)) * 64;
#pragma unroll
        for (int m = 0; m < 4; ++m) {
            int c = m * 16 + g * 4;
            float v0 = fmaxf(acc[m][0] + bias[c], 0.f);
            float v1 = fmaxf(acc[m][1] + bias[c + 1], 0.f);
            float v2 = fmaxf(acc[m][2] + bias[c + 2], 0.f);
            float v3 = fmaxf(acc[m][3] + bias[c + 3], 0.f);
            uint2 pk;
            pk.x = (uint32)f2bf(v0) | ((uint32)f2bf(v1) << 16);
            pk.y = (uint32)f2bf(v2) | ((uint32)f2bf(v3) << 16);
            *(uint2*)(ob + c) = pk;
        }
    } else {
        // MODE 2: relu(conv_c) then fused 1x1(64->4) + sigmoid to d_out.
        float v[4][4];
#pragma unroll
        for (int m = 0; m < 4; ++m) {
            int c = m * 16 + g * 4;
#pragma unroll
            for (int r = 0; r < 4; ++r)
                v[m][r] = fmaxf(acc[m][r] + bias[c + r], 0.f);
        }
        float s[4];
#pragma unroll
        for (int oc = 0; oc < 4; ++oc) {
            float t = 0.0f;
#pragma unroll
            for (int m = 0; m < 4; ++m) {
                int c = m * 16 + g * 4;
#pragma unroll
                for (int r = 0; r < 4; ++r)
                    t += wd[oc * 64 + c + r] * v[m][r];
            }
            t += __shfl_xor(t, 16);
            t += __shfl_xor(t, 32);
            s[oc] = t;
        }
        if (g == 0) {
            float* od = (float*)outp;
            od[1536 + (size_t)(b * 2 + 0) * 16384 + ij] = sigmoidf(s[2] + bd[2]);  // iou ch0
            od[1536 + (size_t)(b * 2 + 1) * 16384 + ij] = sigmoidf(s[3] + bd[3]);  // iou ch1
            od[132608 + (size_t)b * 16384 + ij] = sigmoidf(s[0] + bd[0]);          // prop_start
            od[198144 + (size_t)b * 16384 + ij] = sigmoidf(s[1] + bd[1]);          // prop_end
        }
    }
}

// ---------------------------------------------------------------------------
extern "C" void kernel_launch(void* const* d_in, const int* in_sizes, int n_in,
                              void* d_out, int out_size, void* d_ws, size_t ws_size,
                              hipStream_t stream)
{
    const float* x   = (const float*)d_in[0];
    const float* w1  = (const float*)d_in[1];
    const float* b1  = (const float*)d_in[2];
    const float* w2  = (const float*)d_in[3];
    const float* b2  = (const float*)d_in[4];
    const float* w3  = (const float*)d_in[5];
    const float* b3  = (const float*)d_in[6];
    const float* w3d = (const float*)d_in[7];
    const float* b3d = (const float*)d_in[8];
    const float* wa  = (const float*)d_in[9];
    const float* ba  = (const float*)d_in[10];
    const float* wb  = (const float*)d_in[11];
    const float* bb  = (const float*)d_in[12];
    const float* wc  = (const float*)d_in[13];
    const float* bc  = (const float*)d_in[14];
    const float* wd  = (const float*)d_in[15];
    const float* bd  = (const float*)d_in[16];
    const float* sm  = (const float*)d_in[17];
    float* outp = (float*)d_out;
    char* ws = (char*)d_ws;

    // workspace layout (with aliasing; peak ~127.3 MB)
    float*  h1    = (float*)(ws + 0);              //  1,048,576 B
    float*  h     = (float*)(ws + 1048576);        //    262,144 B
    ushort* h2t   = (ushort*)(ws + 1310720);       // 16,777,216 B
    uint32* ecnt  = (uint32*)(ws + 18087936);      //  2,097,152 B
    uint8_t* et   = (uint8_t*)(ws + 20185088);     //  4,194,304 B
    float*  ewf   = (float*)(ws + 24379392);       // 16,777,216 B (dead after e2)
    uint32* cntij = (uint32*)(ws + 41156608);      //     65,536 B
    int2*   taps  = (int2*)(ws + 41222144);        // 25,165,824 B
    ushort* cm2   = (ushort*)(ws + 66387968);      // 67,108,864 B  [ij][bo]
    ushort* p1b   = (ushort*)(ws + 1310720);       // 16,777,216 B (aliases h2t; dead then)
    ushort* p2b   = (ushort*)(ws + 41222144);      //  8,388,608 B (aliases taps; dead then)
    // transient weight transposes, all inside the ewf zone (24,379,392..41,156,608):
    float*  w1T   = (float*)(ws + 24379392);       //  1,228,800 B (dead before e1)
    float*  w2T   = (float*)(ws + 25608192);       //    786,432 B (dead before e1)
    float*  w3dT  = (float*)(ws + 24379392);       //  8,388,608 B (written after e2)
    ushort* wbB   = (ushort*)(ws + 34865152);      //    147,456 B (written after e2)
    ushort* wcB   = (ushort*)(ws + 35012608);      //     73,728 B
    ushort* waB   = (ushort*)(ws + 35307520);      //    131,072 B (ends < cntij)

    dim3 blk(256);
    k_prep1<<<1968, blk, 0, stream>>>(w1, w1T, w2, w2T);
    k_conv1d_relu<<<dim3(32, 4), blk, 0, stream>>>(x, w1T, b1, h1, 200, 400, 512);
    k_conv1d_relu<<<dim3(8, 4), blk, 0, stream>>>(h1, w2T, b2, h, 512, 512, 128);
    k_x4<<<1, 512, 0, stream>>>(h, w3, b3, outp);
    k_e1<<<2048, blk, 0, stream>>>(sm, ecnt, et, ewf);
    k_e2<<<8192, 64, 0, stream>>>(ecnt, et, ewf, cntij, taps);
    k_prep2<<<1200, blk, 0, stream>>>(w3d, w3dT, wb, wbB, wc, wcB, wa, waB);
    k_h2<<<dim3(8, 32, 4), blk, 0, stream>>>(h, w3dT, h2t);
    k_bm<<<dim3(8, 1024), dim3(64), 0, stream>>>(h2t, taps, cntij, b3d, cm2, 0);
    k_bm<<<dim3(8, 1024), dim3(64), 0, stream>>>(h2t, taps, cntij, b3d, cm2, 1024);
    k_convaM<<<dim3(256, 4), blk, 0, stream>>>(cm2, waB, ba, p1b);
    k_conv3x3M<128, 1><<<dim3(256, 4), blk, 0, stream>>>(p1b, wbB, bb, (void*)p2b, nullptr, nullptr);
    k_conv3x3M<64, 2><<<dim3(256, 4), blk, 0, stream>>>(p2b, wcB, bc, (void*)outp, wd, bd);
}

// Round 16
// 797.500 us; speedup vs baseline: 1.1085x; 1.1085x over previous
//
#include <hip/hip_runtime.h>
#include <hip/hip_bf16.h>
#include <stdint.h>

// ---------------------------------------------------------------------------
// Problem geometry
//   x (4,400,128) -> conv1d(200->512,k3,p1,relu) -> conv1d(512->128,k3,p1,relu) = h
//   x4 = sigmoid(0.01*conv1d(h, w3(3,128,1))) -> outputs xc(ch2), xb_start(ch0), xb_end(ch1)
//   cm = einsum('bct,tm->bcm', h, mask) ; conv3d(w3d, stride 32) + b3d, relu
//     == relu(b3d[o] + sum_{s,t} mask[t,s,i,j] * H2[b,o,s,t])   (<=6 taps/(s,i,j))
//   then 1x1(512->128,relu) [MFMA], 3x3(128->64,relu) [MFMA], 3x3(64->64,relu)
//   [MFMA, fused with final 1x1 64->4 sigmoid via cross-lane reduce]
//   outputs (float32): xc,xb_start,xb_end (3*512) | iou (4,2,128,128) | prop_start | prop_end
//
// cm stored TRANSPOSED: cm2[ij][bo]. k_bm (round-13 proven, single dispatch):
// 64-thr single-wave blocks, bo-quad per thread, per-column tap loop, LDS
// broadcast, grid (x=boT 8 -> XCD-pinned 2MB h2t slice, y=2048) = 16384
// blocks = 2x wave-capacity oversubscription (measured essential: split into
// two 1x-capacity halves ran 222+222 vs 284 single).
// MFMA fragment mapping (HW-validated by round-10 conva): A row=lane&15,
// k=(lane>>4)*8+e; B col=lane&15; D col=lane&15, row=(lane>>4)*4+reg.
// ---------------------------------------------------------------------------

typedef unsigned int uint32;
typedef __attribute__((ext_vector_type(8))) short bf16x8;
typedef __attribute__((ext_vector_type(4))) float f32x4;

__device__ __forceinline__ float bf2f(ushort u) {
    return __uint_as_float(((uint32)u) << 16);
}
__device__ __forceinline__ ushort f2bf(float f) {
    uint32 x = __float_as_uint(f);
    uint32 r = (x + 0x7FFFu + ((x >> 16) & 1u)) >> 16;
    return (ushort)r;
}
__device__ __forceinline__ float sigmoidf(float x) {
    return 1.0f / (1.0f + __expf(-x));
}

// ---------------------------------------------------------------------------
// k_prep1: conv1d weight transposes (before conv1d).
//   sec A (blocks 0..1199):   w1 (512,200,3) -> w1T[(c*3+k)][512]
//   sec B (blocks 1200..1967): w2 (128,512,3) -> w2T[(c*3+k)][128]
// ---------------------------------------------------------------------------
__global__ __launch_bounds__(256) void k_prep1(
    const float* __restrict__ w1, float* __restrict__ w1T,
    const float* __restrict__ w2, float* __restrict__ w2T)
{
    int bid = blockIdx.x;
    if (bid < 1200) {
        int n = bid * 256 + threadIdx.x;
        if (n < 600 * 512) {
            int o = n % 512, rem = n / 512;
            w1T[n] = w1[(size_t)o * 600 + rem];
        }
    } else {
        int n = (bid - 1200) * 256 + threadIdx.x;
        if (n < 1536 * 128) {
            int o = n % 128, rem = n / 128;
            w2T[n] = w2[(size_t)o * 1536 + rem];
        }
    }
}

// ---------------------------------------------------------------------------
// k_prep2 (after e2; ewf zone dead):
//   sec A (0..511):    w3d (512,128,32) -> w3dT[s][o][c], LDS-tiled (o = bid)
//   sec B (512..799):  wb -> wbB bf16 [kk][64][128]
//   sec C (800..943):  wc -> wcB bf16 [kk][64][64]
//   sec D (944..1199): wa -> waB bf16 row-major
// ---------------------------------------------------------------------------
__global__ __launch_bounds__(256) void k_prep2(
    const float* __restrict__ w3d, float* __restrict__ w3dT,
    const float* __restrict__ wb, ushort* __restrict__ wbB,
    const float* __restrict__ wc, ushort* __restrict__ wcB,
    const float* __restrict__ wa, ushort* __restrict__ waB)
{
    int bid = blockIdx.x;
    if (bid < 512) {
        __shared__ float lt[128 * 33];
        int o = bid;
        for (int n = threadIdx.x; n < 4096; n += 256) {
            // n = c*32 + s (coalesced read)
            lt[(n >> 5) * 33 + (n & 31)] = w3d[(size_t)o * 4096 + n];
        }
        __syncthreads();
        for (int n = threadIdx.x; n < 4096; n += 256) {
            // n = s*128 + c (coalesced write)
            int s = n >> 7, c = n & 127;
            w3dT[((size_t)(s * 512 + o)) * 128 + c] = lt[c * 33 + s];
        }
    } else if (bid < 800) {
        int n = (bid - 512) * 256 + threadIdx.x;
        if (n < 64 * 128 * 9) {
            int kk = n % 9, rest = n / 9;
            int cin = rest & 127, cout = rest >> 7;
            wbB[((size_t)(kk * 64 + cout)) * 128 + cin] = f2bf(wb[n]);
        }
    } else if (bid < 944) {
        int n = (bid - 800) * 256 + threadIdx.x;
        if (n < 64 * 64 * 9) {
            int kk = n % 9, rest = n / 9;
            int cin = rest & 63, cout = rest >> 6;
            wcB[((size_t)(kk * 64 + cout)) * 64 + cin] = f2bf(wc[n]);
        }
    } else {
        int n = (bid - 944) * 256 + threadIdx.x;
        waB[n] = f2bf(wa[n]);
    }
}

// ---------------------------------------------------------------------------
// conv1d (k=3, pad=1, relu). Block: 16 out-channels x 128 t. Grid (COUT/16, B).
// ---------------------------------------------------------------------------
__global__ __launch_bounds__(256) void k_conv1d_relu(
    const float* __restrict__ in, const float* __restrict__ wT,
    const float* __restrict__ bias, float* __restrict__ out,
    int CIN, int in_batch_stride, int COUT)
{
    __shared__ float lx[64 * 132];   // [c][0..127 data, 128 = zero pad]
    __shared__ float lws[64 * 48];   // [c][k][16 o]
    int b  = blockIdx.y;
    int ooL = threadIdx.x >> 4;
    int o  = blockIdx.x * 16 + ooL;
    int tg = threadIdx.x & 15;
    int t0 = tg * 8;

    float acc[8];
#pragma unroll
    for (int k = 0; k < 8; ++k) acc[k] = 0.0f;

    for (int c0 = 0; c0 < CIN; c0 += 64) {
        int nc = CIN - c0; if (nc > 64) nc = 64;
        __syncthreads();
        for (int n = threadIdx.x; n < nc * 32; n += 256) {
            int cl = n >> 5, q = n & 31;
            float4 v = *(const float4*)(in + ((size_t)(b * in_batch_stride + c0 + cl)) * 128 + q * 4);
            *(float4*)(&lx[cl * 132 + q * 4]) = v;
        }
        for (int cl = threadIdx.x; cl < nc; cl += 256) lx[cl * 132 + 128] = 0.0f;
        for (int n = threadIdx.x; n < nc * 48; n += 256) {
            int cl = n / 48, r = n - cl * 48;       // r = k*16 + oo
            lws[n] = wT[((size_t)(c0 + cl) * 3 + (r >> 4)) * COUT + blockIdx.x * 16 + (r & 15)];
        }
        __syncthreads();

        for (int cl = 0; cl < nc; ++cl) {
            const float* wrow = &lws[cl * 48 + ooL];
            float w0 = wrow[0], w1 = wrow[16], w2 = wrow[32];
            const float* row = &lx[cl * 132];
            float xv[10];
            if (t0 == 0) {
                xv[0] = 0.0f;
#pragma unroll
                for (int k = 1; k < 10; ++k) xv[k] = row[k - 1];
            } else {
#pragma unroll
                for (int k = 0; k < 10; ++k) xv[k] = row[t0 - 1 + k];
            }
#pragma unroll
            for (int k = 0; k < 8; ++k)
                acc[k] += w0 * xv[k] + w1 * xv[k + 1] + w2 * xv[k + 2];
        }
    }
    float bo = bias[o];
#pragma unroll
    for (int k = 0; k < 8; ++k) {
        float v = acc[k] + bo;
        out[((size_t)(b * COUT + o)) * 128 + t0 + k] = v > 0.0f ? v : 0.0f;
    }
}

// ---------------------------------------------------------------------------
// x4 head -> d_out[0:1536] floats: (xc=ch2 | xb_start=ch0 | xb_end=ch1)
// ---------------------------------------------------------------------------
__global__ void k_x4(const float* __restrict__ h, const float* __restrict__ w3,
                     const float* __restrict__ b3, float* __restrict__ outp)
{
    int tid = threadIdx.x;
    int b = tid >> 7, t = tid & 127;
    float a0 = 0.f, a1 = 0.f, a2 = 0.f;
    for (int c = 0; c < 128; ++c) {
        float hv = h[((size_t)(b * 128 + c)) * 128 + t];
        a0 += w3[c] * hv;
        a1 += w3[128 + c] * hv;
        a2 += w3[256 + c] * hv;
    }
    float s0 = sigmoidf(0.01f * (a0 + b3[0]));
    float s1 = sigmoidf(0.01f * (a1 + b3[1]));
    float s2 = sigmoidf(0.01f * (a2 + b3[2]));
    int bt = b * 128 + t;
    outp[bt]        = s2;   // xc
    outp[512 + bt]  = s0;   // xb_start
    outp[1024 + bt] = s1;   // xb_end
}

// ---------------------------------------------------------------------------
// H2t[(s*128+t)*2048 + b*512+o] = bf16( sum_c w3dT[s][o][c]*h[b,c,t] )
// ---------------------------------------------------------------------------
__global__ __launch_bounds__(256) void k_h2(
    const float* __restrict__ h, const float* __restrict__ w3dT,
    ushort* __restrict__ h2t)
{
    __shared__ float lw[64 * 132];     // [o][c] stride 132
    __shared__ float lhs[32 * 132];    // [c_local][t] ; reused as out stage
    int ot = blockIdx.x, s = blockIdx.y, b = blockIdx.z;
    int o0 = ot * 64;

    for (int n = threadIdx.x; n < 2048; n += 256) {
        int o = n >> 5, q = n & 31;
        *(float4*)(&lw[o * 132 + q * 4]) =
            *(const float4*)(w3dT + ((size_t)(s * 512 + o0 + o)) * 128 + q * 4);
    }

    int og = threadIdx.x >> 4, tg = threadIdx.x & 15;
    int o0t = og * 4, t0 = tg * 8;
    float acc[4][8];
#pragma unroll
    for (int oo = 0; oo < 4; ++oo)
#pragma unroll
        for (int k = 0; k < 8; ++k) acc[oo][k] = 0.0f;

    for (int c0 = 0; c0 < 128; c0 += 32) {
        __syncthreads();
        for (int n = threadIdx.x; n < 1024; n += 256) {
            int cl = n >> 5, q = n & 31;
            *(float4*)(&lhs[cl * 132 + q * 4]) =
                *(const float4*)(h + ((size_t)(b * 128 + c0 + cl)) * 128 + q * 4);
        }
        __syncthreads();
        for (int cl = 0; cl < 32; ++cl) {
            float hv[8];
#pragma unroll
            for (int k = 0; k < 8; ++k) hv[k] = lhs[cl * 132 + t0 + k];
#pragma unroll
            for (int oo = 0; oo < 4; ++oo) {
                float wv = lw[(o0t + oo) * 132 + c0 + cl];
#pragma unroll
                for (int k = 0; k < 8; ++k) acc[oo][k] += wv * hv[k];
            }
        }
    }
    __syncthreads();
    ushort* lout = (ushort*)lhs;       // [t*64 + o]
#pragma unroll
    for (int oo = 0; oo < 4; ++oo)
#pragma unroll
        for (int k = 0; k < 8; ++k)
            lout[(t0 + k) * 64 + o0t + oo] = f2bf(acc[oo][k]);
    __syncthreads();
    for (int n = threadIdx.x; n < 8192; n += 256) {
        int t = n >> 6, o = n & 63;
        h2t[(size_t)(s * 128 + t) * 2048 + b * 512 + o0 + o] = lout[n];
    }
}

// ---------------------------------------------------------------------------
// E1: per mask column m=(s,i,j), collect nonzero (t,w) taps (<=6 exist, cap 8).
// ---------------------------------------------------------------------------
__global__ __launch_bounds__(256) void k_e1(
    const float* __restrict__ mask, uint32* __restrict__ ecnt,
    uint8_t* __restrict__ et, float* __restrict__ ew)
{
    uint32 m = blockIdx.x * 256 + threadIdx.x;
    int cnt = 0;
    for (int t = 0; t < 128; ++t) {
        float w = mask[(size_t)t * 524288 + m];
        if (w != 0.0f) {
            if (cnt < 8) {
                et[(size_t)m * 8 + cnt] = (uint8_t)t;
                ew[(size_t)m * 8 + cnt] = w;
            }
            cnt++;
        }
    }
    ecnt[m] = (uint32)(cnt < 8 ? cnt : 8);
}

// ---------------------------------------------------------------------------
// E2: merge per (i,j): taps over all 32 s -> packed {w_bits, byte_off} (<=192).
// ---------------------------------------------------------------------------
__global__ void k_e2(const uint32* __restrict__ ecnt, const uint8_t* __restrict__ et,
                     const float* __restrict__ ew, uint32* __restrict__ cntij,
                     int2* __restrict__ taps)
{
    int lane = threadIdx.x & 31;
    int col = blockIdx.x * 2 + (threadIdx.x >> 5);
    uint32 m = (uint32)lane * 16384u + (uint32)col;
    int c = (int)ecnt[m];
    int v = c;
    for (int d = 1; d < 32; d <<= 1) {
        int t = __shfl_up(v, d, 32);
        if (lane >= d) v += t;
    }
    int off = v - c;
    if (lane == 31) cntij[col] = (uint32)v;
    for (int k = 0; k < c; ++k) {
        int2 r;
        r.x = __float_as_int(ew[(size_t)m * 8 + k]);
        r.y = ((lane << 7) + (int)et[(size_t)m * 8 + k]) << 12;   // st * 4096 bytes
        taps[(size_t)col * 192 + off + k] = r;
    }
}

// ---------------------------------------------------------------------------
// k_bm (round-13 proven, single dispatch): cm2[ij, bo] = relu(b3d + sum w*H2t)
// 64-thr single-wave blocks; bo-quad per thread (dwordx2 = 4 bf16 = 4 MACs).
// Per-column tap loop (unroll 8); taps broadcast from 6 KB LDS.
// Grid (x=boT 8 -> XCD-pinned 2MB h2t slice, y = i*16 + oct8) = 16384 blocks.
// ---------------------------------------------------------------------------
__global__ __launch_bounds__(64) void k_bm(
    const ushort* __restrict__ h2t, const int2* __restrict__ taps,
    const uint32* __restrict__ cntij, const float* __restrict__ b3d,
    ushort* __restrict__ cm2)
{
    __shared__ int2 tl[4 * 192];        // 6,144 B
    int boT = blockIdx.x;
    int i = blockIdx.y >> 4, oc = blockIdx.y & 15;
    int tid = threadIdx.x;
    int bo0 = boT * 256 + tid * 4;
    const char* hb = (const char*)h2t + (size_t)bo0 * 2;
    float4 bias = *(const float4*)(b3d + (bo0 & 511));

    for (int jc = 0; jc < 2; ++jc) {
        int j0 = oc * 8 + jc * 4;
        int ij0 = i * 128 + j0;
        int cnts[4];
#pragma unroll
        for (int c = 0; c < 4; ++c) cnts[c] = (int)cntij[ij0 + c];
        __syncthreads();   // previous chunk's readers done before tl overwrite
        for (int n = tid; n < 768; n += 64) {
            int c = n / 192, k = n - c * 192;
            if (k < cnts[c]) tl[n] = taps[(size_t)(ij0 + c) * 192 + k];
        }
        __syncthreads();
#pragma unroll 1
        for (int c = 0; c < 4; ++c) {
            int cnt = cnts[c];
            const int2* tp = &tl[c * 192];
            float a0 = 0.f, a1 = 0.f, a2 = 0.f, a3 = 0.f;
#pragma unroll 8
            for (int k = 0; k < cnt; ++k) {
                int2 r = tp[k];
                uint2 hv = *(const uint2*)(hb + (uint32)r.y);
                float w = __int_as_float(r.x);
                a0 += w * __uint_as_float(hv.x << 16);
                a1 += w * __uint_as_float(hv.x & 0xffff0000u);
                a2 += w * __uint_as_float(hv.y << 16);
                a3 += w * __uint_as_float(hv.y & 0xffff0000u);
            }
            float v0 = fmaxf(a0 + bias.x, 0.f);
            float v1 = fmaxf(a1 + bias.y, 0.f);
            float v2 = fmaxf(a2 + bias.z, 0.f);
            float v3 = fmaxf(a3 + bias.w, 0.f);
            uint64_t pr = (uint64_t)((uint32)f2bf(v0) | ((uint32)f2bf(v1) << 16))
                        | ((uint64_t)((uint32)f2bf(v2) | ((uint32)f2bf(v3) << 16)) << 32);
            __builtin_nontemporal_store(pr, (uint64_t*)(cm2 + (size_t)(ij0 + c) * 2048 + bo0));
        }
    }
}

// ---------------------------------------------------------------------------
// conv-a via MFMA: p1b[b][ij][c] = bf16(relu(ba[c] + sum_o waB[c,o]*cm2[ij,b*512+o]))
// ---------------------------------------------------------------------------
__global__ __launch_bounds__(256) void k_convaM(
    const ushort* __restrict__ cm2, const ushort* __restrict__ waB,
    const float* __restrict__ ba, ushort* __restrict__ p1b)
{
    int b = blockIdx.y;
    int wv = threadIdx.x >> 6, l = threadIdx.x & 63;
    int ij0 = blockIdx.x * 64 + wv * 16;
    int l15 = l & 15, g = l >> 4;

    f32x4 acc[8];
#pragma unroll
    for (int m = 0; m < 8; ++m) acc[m] = (f32x4){0.f, 0.f, 0.f, 0.f};

    const ushort* bbase = cm2 + (size_t)(ij0 + l15) * 2048 + b * 512 + g * 8;
    const ushort* abase = waB + (size_t)l15 * 512 + g * 8;

#pragma unroll 2
    for (int o0 = 0; o0 < 512; o0 += 32) {
        bf16x8 bv = *(const bf16x8*)(bbase + o0);
#pragma unroll
        for (int m = 0; m < 8; ++m) {
            bf16x8 av = *(const bf16x8*)(abase + (size_t)(m * 16) * 512 + o0);
            acc[m] = __builtin_amdgcn_mfma_f32_16x16x32_bf16(av, bv, acc[m], 0, 0, 0);
        }
    }

    int ij = ij0 + l15;
    ushort* ob = p1b + ((size_t)(b * 16384 + ij)) * 128;
#pragma unroll
    for (int m = 0; m < 8; ++m) {
        int c = m * 16 + g * 4;
        float v0 = fmaxf(acc[m][0] + ba[c], 0.f);
        float v1 = fmaxf(acc[m][1] + ba[c + 1], 0.f);
        float v2 = fmaxf(acc[m][2] + ba[c + 2], 0.f);
        float v3 = fmaxf(acc[m][3] + ba[c + 3], 0.f);
        uint2 pk;
        pk.x = (uint32)f2bf(v0) | ((uint32)f2bf(v1) << 16);
        pk.y = (uint32)f2bf(v2) | ((uint32)f2bf(v3) << 16);
        *(uint2*)(ob + c) = pk;
    }
}

// ---------------------------------------------------------------------------
// 3x3 conv via MFMA (implicit GEMM over 9 shifted taps).
// inB: [b][ij][CIN] bf16. wB: [kk][64][CIN] bf16. Wave owns 64c x 16ij.
// MODE 1: bf16 out [b][ij][64]. MODE 2: fused final 1x1(64->4)+sigmoid.
// ---------------------------------------------------------------------------
template <int CIN, int MODE>
__global__ __launch_bounds__(256) void k_conv3x3M(
    const ushort* __restrict__ inB, const ushort* __restrict__ wB,
    const float* __restrict__ bias, void* __restrict__ outp,
    const float* __restrict__ wd, const float* __restrict__ bd)
{
    int b = blockIdx.y;
    int wv = threadIdx.x >> 6, l = threadIdx.x & 63;
    int l15 = l & 15, g = l >> 4;
    int tile = blockIdx.x;                 // 0..255
    int i = tile >> 1;
    int j = (tile & 1) * 64 + wv * 16 + l15;
    const ushort* inb = inB + (size_t)b * 16384 * CIN;

    f32x4 acc[4];
#pragma unroll
    for (int m = 0; m < 4; ++m) acc[m] = (f32x4){0.f, 0.f, 0.f, 0.f};

#pragma unroll
    for (int ky = 0; ky < 3; ++ky) {
        int ii = i + ky - 1;
        if (ii < 0 || ii >= 128) continue;      // uniform per block
#pragma unroll
        for (int kx = 0; kx < 3; ++kx) {
            int jv = j + kx - 1;
            bool ok = (jv >= 0) && (jv < 128);  // per-lane
            const ushort* bp = inb + (size_t)(ii * 128 + jv) * CIN + g * 8;
            const ushort* ap = wB + (size_t)((ky * 3 + kx) * 64 + l15) * CIN + g * 8;
#pragma unroll
            for (int o0 = 0; o0 < CIN; o0 += 32) {
                bf16x8 bv;
                if (ok) bv = *(const bf16x8*)(bp + o0);
                else    bv = (bf16x8){0, 0, 0, 0, 0, 0, 0, 0};
#pragma unroll
                for (int m = 0; m < 4; ++m) {
                    bf16x8 av = *(const bf16x8*)(ap + (size_t)(m * 16) * CIN + o0);
                    acc[m] = __builtin_amdgcn_mfma_f32_16x16x32_bf16(av, bv, acc[m], 0, 0, 0);
                }
            }
        }
    }

    int ij = i * 128 + j;
    if (MODE == 1) {
        ushort* ob = (ushort*)outp + ((size_t)(b * 16384 + ij)) * 64;
#pragma unroll
        for (int m = 0; m < 4; ++m) {
            int c = m * 16 + g * 4;
            float v0 = fmaxf(acc[m][0] + bias[c], 0.f);
            float v1 = fmaxf(acc[m][1] + bias[c + 1], 0.f);
            float v2 = fmaxf(acc[m][2] + bias[c + 2], 0.f);
            float v3 = fmaxf(acc[m][3] + bias[c + 3], 0.f);
            uint2 pk;
            pk.x = (uint32)f2bf(v0) | ((uint32)f2bf(v1) << 16);
            pk.y = (uint32)f2bf(v2) | ((uint32)f2bf(v3) << 16);
            *(uint2*)(ob + c) = pk;
        }
    } else {
        // MODE 2: relu(conv_c) then fused 1x1(64->4) + sigmoid to d_out.
        float v[4][4];
#pragma unroll
        for (int m = 0; m < 4; ++m) {
            int c = m * 16 + g * 4;
#pragma unroll
            for (int r = 0; r < 4; ++r)
                v[m][r] = fmaxf(acc[m][r] + bias[c + r], 0.f);
        }
        float s[4];
#pragma unroll
        for (int oc = 0; oc < 4; ++oc) {
            float t = 0.0f;
#pragma unroll
            for (int m = 0; m < 4; ++m) {
                int c = m * 16 + g * 4;
#pragma unroll
                for (int r = 0; r < 4; ++r)
                    t += wd[oc * 64 + c + r] * v[m][r];
            }
            t += __shfl_xor(t, 16);
            t += __shfl_xor(t, 32);
            s[oc] = t;
        }
        if (g == 0) {
            float* od = (float*)outp;
            od[1536 + (size_t)(b * 2 + 0) * 16384 + ij] = sigmoidf(s[2] + bd[2]);  // iou ch0
            od[1536 + (size_t)(b * 2 + 1) * 16384 + ij] = sigmoidf(s[3] + bd[3]);  // iou ch1
            od[132608 + (size_t)b * 16384 + ij] = sigmoidf(s[0] + bd[0]);          // prop_start
            od[198144 + (size_t)b * 16384 + ij] = sigmoidf(s[1] + bd[1]);          // prop_end
        }
    }
}

// ---------------------------------------------------------------------------
extern "C" void kernel_launch(void* const* d_in, const int* in_sizes, int n_in,
                              void* d_out, int out_size, void* d_ws, size_t ws_size,
                              hipStream_t stream)
{
    const float* x   = (const float*)d_in[0];
    const float* w1  = (const float*)d_in[1];
    const float* b1  = (const float*)d_in[2];
    const float* w2  = (const float*)d_in[3];
    const float* b2  = (const float*)d_in[4];
    const float* w3  = (const float*)d_in[5];
    const float* b3  = (const float*)d_in[6];
    const float* w3d = (const float*)d_in[7];
    const float* b3d = (const float*)d_in[8];
    const float* wa  = (const float*)d_in[9];
    const float* ba  = (const float*)d_in[10];
    const float* wb  = (const float*)d_in[11];
    const float* bb  = (const float*)d_in[12];
    const float* wc  = (const float*)d_in[13];
    const float* bc  = (const float*)d_in[14];
    const float* wd  = (const float*)d_in[15];
    const float* bd  = (const float*)d_in[16];
    const float* sm  = (const float*)d_in[17];
    float* outp = (float*)d_out;
    char* ws = (char*)d_ws;

    // workspace layout (with aliasing; peak ~127.3 MB)
    float*  h1    = (float*)(ws + 0);              //  1,048,576 B
    float*  h     = (float*)(ws + 1048576);        //    262,144 B
    ushort* h2t   = (ushort*)(ws + 1310720);       // 16,777,216 B
    uint32* ecnt  = (uint32*)(ws + 18087936);      //  2,097,152 B
    uint8_t* et   = (uint8_t*)(ws + 20185088);     //  4,194,304 B
    float*  ewf   = (float*)(ws + 24379392);       // 16,777,216 B (dead after e2)
    uint32* cntij = (uint32*)(ws + 41156608);      //     65,536 B
    int2*   taps  = (int2*)(ws + 41222144);        // 25,165,824 B
    ushort* cm2   = (ushort*)(ws + 66387968);      // 67,108,864 B  [ij][bo]
    ushort* p1b   = (ushort*)(ws + 1310720);       // 16,777,216 B (aliases h2t; dead then)
    ushort* p2b   = (ushort*)(ws + 41222144);      //  8,388,608 B (aliases taps; dead then)
    // transient weight transposes, all inside the ewf zone (24,379,392..41,156,608):
    float*  w1T   = (float*)(ws + 24379392);       //  1,228,800 B (dead before e1)
    float*  w2T   = (float*)(ws + 25608192);       //    786,432 B (dead before e1)
    float*  w3dT  = (float*)(ws + 24379392);       //  8,388,608 B (written after e2)
    ushort* wbB   = (ushort*)(ws + 34865152);      //    147,456 B (written after e2)
    ushort* wcB   = (ushort*)(ws + 35012608);      //     73,728 B
    ushort* waB   = (ushort*)(ws + 35307520);      //    131,072 B (ends < cntij)

    dim3 blk(256);
    k_prep1<<<1968, blk, 0, stream>>>(w1, w1T, w2, w2T);
    k_conv1d_relu<<<dim3(32, 4), blk, 0, stream>>>(x, w1T, b1, h1, 200, 400, 512);
    k_conv1d_relu<<<dim3(8, 4), blk, 0, stream>>>(h1, w2T, b2, h, 512, 512, 128);
    k_x4<<<1, 512, 0, stream>>>(h, w3, b3, outp);
    k_e1<<<2048, blk, 0, stream>>>(sm, ecnt, et, ewf);
    k_e2<<<8192, 64, 0, stream>>>(ecnt, et, ewf, cntij, taps);
    k_prep2<<<1200, blk, 0, stream>>>(w3d, w3dT, wb, wbB, wc, wcB, wa, waB);
    k_h2<<<dim3(8, 32, 4), blk, 0, stream>>>(h, w3dT, h2t);
    k_bm<<<dim3(8, 2048), dim3(64), 0, stream>>>(h2t, taps, cntij, b3d, cm2);
    k_convaM<<<dim3(256, 4), blk, 0, stream>>>(cm2, waB, ba, p1b);
    k_conv3x3M<128, 1><<<dim3(256, 4), blk, 0, stream>>>(p1b, wbB, bb, (void*)p2b, nullptr, nullptr);
    k_conv3x3M<64, 2><<<dim3(256, 4), blk, 0, stream>>>(p2b, wcB, bc, (void*)outp, wd, bd);
}

// Round 17
// 616.094 us; speedup vs baseline: 1.4349x; 1.2944x over previous
//
#include <hip/hip_runtime.h>
#include <hip/hip_bf16.h>
#include <stdint.h>

// ---------------------------------------------------------------------------
// Problem geometry
//   x (4,400,128) -> conv1d(200->512,k3,p1,relu) [MFMA GEMM via im2col]
//   -> conv1d(512->128,k3,p1,relu) [3-tap implicit MFMA] = hT (bf16 [b,t][c])
//   x4 = sigmoid(0.01*conv1d(h, w3)) -> xc/xb_start/xb_end
//   H2t[st][bo] = sum_c w3d[o,c,s]*h[b,c,t]  [MFMA, K=c contiguous]
//   cm2[ij][bo] = relu(b3d + sparse-mask contraction of H2t)  [k_bm]
//   then 1x1(512->128) [MFMA], 3x3(128->64) [MFMA], 3x3(64->64)+1x1(64->4)
//   sigmoid fused [MFMA + cross-lane reduce]
//   outputs (float32): xc,xb_start,xb_end | iou | prop_start | prop_end
//
// k_bm (proven config, untouched): 64-thr single-wave blocks, bo-quad/thread,
// grid (8 XCD-pinned, 2048) = 2x wave-capacity oversubscription.
// MFMA fragment mapping (HW-validated): A row=lane&15, k=(lane>>4)*8+e;
// B col=lane&15; D col=lane&15, row=(lane>>4)*4+reg.
// e1 skips end<start columns (identically zero by mask construction).
// ---------------------------------------------------------------------------

typedef unsigned int uint32;
typedef __attribute__((ext_vector_type(8))) short bf16x8;
typedef __attribute__((ext_vector_type(4))) float f32x4;

__device__ __forceinline__ float bf2f(ushort u) {
    return __uint_as_float(((uint32)u) << 16);
}
__device__ __forceinline__ ushort f2bf(float f) {
    uint32 x = __float_as_uint(f);
    uint32 r = (x + 0x7FFFu + ((x >> 16) & 1u)) >> 16;
    return (ushort)r;
}
__device__ __forceinline__ float sigmoidf(float x) {
    return 1.0f / (1.0f + __expf(-x));
}

// ---------------------------------------------------------------------------
// k_prepA (before conv1d chain; lives in ewf zone, dead before e1):
//  A (0..1215):    w1 (512,200,3) -> w1bB bf16 [cout][608] (K zero-padded)
//  B (1216..2431): x im2col -> xcolB bf16 [b*128+t][608], k=cin*3+kp
//  C (2432..3199): w2 (128,512,3) -> w2bB bf16 [kp][cout][cin]
// ---------------------------------------------------------------------------
__global__ __launch_bounds__(256) void k_prepA(
    const float* __restrict__ w1, ushort* __restrict__ w1bB,
    const float* __restrict__ x, ushort* __restrict__ xcolB,
    const float* __restrict__ w2, ushort* __restrict__ w2bB)
{
    int bid = blockIdx.x;
    if (bid < 1216) {
        int n = bid * 256 + threadIdx.x;
        if (n < 311296) {
            int cout = n / 608, k = n - cout * 608;
            float v = (k < 600) ? w1[(size_t)cout * 600 + k] : 0.f;
            w1bB[n] = f2bf(v);
        }
    } else if (bid < 2432) {
        int n = (bid - 1216) * 256 + threadIdx.x;
        if (n < 311296) {
            int row = n / 608, k = n - row * 608;   // row = b*128+t
            float v = 0.f;
            if (k < 600) {
                int cin = k / 3, kp = k - cin * 3;
                int b = row >> 7, t = row & 127;
                int tt = t + kp - 1;
                if (tt >= 0 && tt < 128)
                    v = x[(size_t)b * 51200 + cin * 128 + tt];
            }
            xcolB[n] = f2bf(v);
        }
    } else {
        int n = (bid - 2432) * 256 + threadIdx.x;
        if (n < 196608) {
            int kp = n >> 16;
            int rem = n & 65535;
            int cout = rem >> 9, cin = rem & 511;
            w2bB[n] = f2bf(w2[(size_t)cout * 1536 + cin * 3 + kp]);
        }
    }
}

// ---------------------------------------------------------------------------
// k_gemm1: conv1d_1 as GEMM. M=cout 512, N=(b,t) 512, K=608.
// h1t[n][cout] = bf16(relu(b1 + sum_k w1bB[cout][k]*xcolB[n][k]))
// Grid (8 n-tiles of 64, 4 m-tiles of 128) x 256 thr (4 waves of 16 n).
// ---------------------------------------------------------------------------
__global__ __launch_bounds__(256) void k_gemm1(
    const ushort* __restrict__ xcolB, const ushort* __restrict__ w1bB,
    const float* __restrict__ b1, ushort* __restrict__ h1t)
{
    int nt = blockIdx.x, mt = blockIdx.y;
    int wv = threadIdx.x >> 6, l = threadIdx.x & 63;
    int l15 = l & 15, g = l >> 4;
    int n = nt * 64 + wv * 16 + l15;

    f32x4 acc[8];
#pragma unroll
    for (int m = 0; m < 8; ++m) acc[m] = (f32x4){0.f, 0.f, 0.f, 0.f};

    const ushort* bbase = xcolB + (size_t)n * 608 + g * 8;
    const ushort* abase = w1bB + (size_t)(mt * 128 + l15) * 608 + g * 8;

#pragma unroll 2
    for (int k0 = 0; k0 < 608; k0 += 32) {
        bf16x8 bv = *(const bf16x8*)(bbase + k0);
#pragma unroll
        for (int m = 0; m < 8; ++m) {
            bf16x8 av = *(const bf16x8*)(abase + (size_t)(m * 16) * 608 + k0);
            acc[m] = __builtin_amdgcn_mfma_f32_16x16x32_bf16(av, bv, acc[m], 0, 0, 0);
        }
    }

    ushort* ob = h1t + (size_t)n * 512 + mt * 128;
#pragma unroll
    for (int m = 0; m < 8; ++m) {
        int cl = m * 16 + g * 4;
        int cg = mt * 128 + cl;
        float v0 = fmaxf(acc[m][0] + b1[cg], 0.f);
        float v1 = fmaxf(acc[m][1] + b1[cg + 1], 0.f);
        float v2 = fmaxf(acc[m][2] + b1[cg + 2], 0.f);
        float v3 = fmaxf(acc[m][3] + b1[cg + 3], 0.f);
        uint2 pk;
        pk.x = (uint32)f2bf(v0) | ((uint32)f2bf(v1) << 16);
        pk.y = (uint32)f2bf(v2) | ((uint32)f2bf(v3) << 16);
        *(uint2*)(ob + cl) = pk;
    }
}

// ---------------------------------------------------------------------------
// k_conv1k3: conv1d_2 as 3-tap implicit GEMM (1-D conv3x3M analog).
// hT[n][c] = bf16(relu(b2 + sum_{kp,cin} w2bB[kp][c][cin]*h1t[n+kp-1][cin]))
// M=c 128, N=n 512, K=512/tap. Grid 32 blocks (16 n each) x 4 waves (32 c).
// ---------------------------------------------------------------------------
__global__ __launch_bounds__(256) void k_conv1k3(
    const ushort* __restrict__ h1t, const ushort* __restrict__ w2bB,
    const float* __restrict__ b2, ushort* __restrict__ hT)
{
    int nt = blockIdx.x;
    int wv = threadIdx.x >> 6, l = threadIdx.x & 63;
    int l15 = l & 15, g = l >> 4;
    int n = nt * 16 + l15;
    int t = n & 127;
    int wvoff = wv * 32;

    f32x4 acc[2];
#pragma unroll
    for (int m = 0; m < 2; ++m) acc[m] = (f32x4){0.f, 0.f, 0.f, 0.f};

#pragma unroll
    for (int kp = 0; kp < 3; ++kp) {
        int tt = t + kp - 1;
        bool ok = (tt >= 0) && (tt < 128);
        const ushort* bp = h1t + (size_t)(n + kp - 1) * 512 + g * 8;
        const ushort* ap = w2bB + (size_t)(kp * 128 + wvoff + l15) * 512 + g * 8;
#pragma unroll 4
        for (int k0 = 0; k0 < 512; k0 += 32) {
            bf16x8 bv;
            if (ok) bv = *(const bf16x8*)(bp + k0);
            else    bv = (bf16x8){0, 0, 0, 0, 0, 0, 0, 0};
#pragma unroll
            for (int m = 0; m < 2; ++m) {
                bf16x8 av = *(const bf16x8*)(ap + (size_t)(m * 16) * 512 + k0);
                acc[m] = __builtin_amdgcn_mfma_f32_16x16x32_bf16(av, bv, acc[m], 0, 0, 0);
            }
        }
    }

    ushort* ob = hT + (size_t)n * 128;
#pragma unroll
    for (int m = 0; m < 2; ++m) {
        int c = wvoff + m * 16 + g * 4;
        float v0 = fmaxf(acc[m][0] + b2[c], 0.f);
        float v1 = fmaxf(acc[m][1] + b2[c + 1], 0.f);
        float v2 = fmaxf(acc[m][2] + b2[c + 2], 0.f);
        float v3 = fmaxf(acc[m][3] + b2[c + 3], 0.f);
        uint2 pk;
        pk.x = (uint32)f2bf(v0) | ((uint32)f2bf(v1) << 16);
        pk.y = (uint32)f2bf(v2) | ((uint32)f2bf(v3) << 16);
        *(uint2*)(ob + c) = pk;
    }
}

// ---------------------------------------------------------------------------
// x4 head (reads bf16 hT[b,t][c]) -> d_out[0:1536] floats
// ---------------------------------------------------------------------------
__global__ void k_x4(const ushort* __restrict__ hT, const float* __restrict__ w3,
                     const float* __restrict__ b3, float* __restrict__ outp)
{
    int tid = threadIdx.x;
    int b = tid >> 7, t = tid & 127;
    const ushort* hp = hT + (size_t)(b * 128 + t) * 128;
    float a0 = 0.f, a1 = 0.f, a2 = 0.f;
    for (int c = 0; c < 128; ++c) {
        float hv = bf2f(hp[c]);
        a0 += w3[c] * hv;
        a1 += w3[128 + c] * hv;
        a2 += w3[256 + c] * hv;
    }
    float s0 = sigmoidf(0.01f * (a0 + b3[0]));
    float s1 = sigmoidf(0.01f * (a1 + b3[1]));
    float s2 = sigmoidf(0.01f * (a2 + b3[2]));
    int bt = b * 128 + t;
    outp[bt]        = s2;   // xc
    outp[512 + bt]  = s0;   // xb_start
    outp[1024 + bt] = s1;   // xb_end
}

// ---------------------------------------------------------------------------
// E1: per mask column m=(s,start,end), collect nonzero taps (cap 8).
// Columns with end<start are identically zero by construction: skip the scan.
// ---------------------------------------------------------------------------
__global__ __launch_bounds__(256) void k_e1(
    const float* __restrict__ mask, uint32* __restrict__ ecnt,
    uint8_t* __restrict__ et, float* __restrict__ ew)
{
    uint32 m = blockIdx.x * 256 + threadIdx.x;
    int start = (int)((m >> 7) & 127), end = (int)(m & 127);
    if (end < start) { ecnt[m] = 0; return; }
    int cnt = 0;
    for (int t = 0; t < 128; ++t) {
        float w = mask[(size_t)t * 524288 + m];
        if (w != 0.0f) {
            if (cnt < 8) {
                et[(size_t)m * 8 + cnt] = (uint8_t)t;
                ew[(size_t)m * 8 + cnt] = w;
            }
            cnt++;
        }
    }
    ecnt[m] = (uint32)(cnt < 8 ? cnt : 8);
}

// ---------------------------------------------------------------------------
// E2: merge per (i,j): taps over all 32 s -> packed {w_bits, byte_off} (<=192).
// ---------------------------------------------------------------------------
__global__ void k_e2(const uint32* __restrict__ ecnt, const uint8_t* __restrict__ et,
                     const float* __restrict__ ew, uint32* __restrict__ cntij,
                     int2* __restrict__ taps)
{
    int lane = threadIdx.x & 31;
    int col = blockIdx.x * 2 + (threadIdx.x >> 5);
    uint32 m = (uint32)lane * 16384u + (uint32)col;
    int c = (int)ecnt[m];
    int v = c;
    for (int d = 1; d < 32; d <<= 1) {
        int t = __shfl_up(v, d, 32);
        if (lane >= d) v += t;
    }
    int off = v - c;
    if (lane == 31) cntij[col] = (uint32)v;
    for (int k = 0; k < c; ++k) {
        int2 r;
        r.x = __float_as_int(ew[(size_t)m * 8 + k]);
        r.y = ((lane << 7) + (int)et[(size_t)m * 8 + k]) << 12;   // st * 4096 bytes
        taps[(size_t)col * 192 + off + k] = r;
    }
}

// ---------------------------------------------------------------------------
// k_prep2 (after e2; ewf zone dead):
//   A (0..511):    w3d (512,128,32) -> w3dB bf16 [s][o][c], LDS-tiled
//   B (512..799):  wb -> wbB bf16 [kk][64][128]
//   C (800..943):  wc -> wcB bf16 [kk][64][64]
//   D (944..1199): wa -> waB bf16 row-major
// ---------------------------------------------------------------------------
__global__ __launch_bounds__(256) void k_prep2(
    const float* __restrict__ w3d, ushort* __restrict__ w3dB,
    const float* __restrict__ wb, ushort* __restrict__ wbB,
    const float* __restrict__ wc, ushort* __restrict__ wcB,
    const float* __restrict__ wa, ushort* __restrict__ waB)
{
    int bid = blockIdx.x;
    if (bid < 512) {
        __shared__ float lt[128 * 33];
        int o = bid;
        for (int n = threadIdx.x; n < 4096; n += 256) {
            lt[(n >> 5) * 33 + (n & 31)] = w3d[(size_t)o * 4096 + n];
        }
        __syncthreads();
        for (int n = threadIdx.x; n < 4096; n += 256) {
            int s = n >> 7, c = n & 127;
            w3dB[((size_t)(s * 512 + o)) * 128 + c] = f2bf(lt[c * 33 + s]);
        }
    } else if (bid < 800) {
        int n = (bid - 512) * 256 + threadIdx.x;
        if (n < 64 * 128 * 9) {
            int kk = n % 9, rest = n / 9;
            int cin = rest & 127, cout = rest >> 7;
            wbB[((size_t)(kk * 64 + cout)) * 128 + cin] = f2bf(wb[n]);
        }
    } else if (bid < 944) {
        int n = (bid - 800) * 256 + threadIdx.x;
        if (n < 64 * 64 * 9) {
            int kk = n % 9, rest = n / 9;
            int cin = rest & 63, cout = rest >> 6;
            wcB[((size_t)(kk * 64 + cout)) * 64 + cin] = f2bf(wc[n]);
        }
    } else {
        int n = (bid - 944) * 256 + threadIdx.x;
        waB[n] = f2bf(wa[n]);
    }
}

// ---------------------------------------------------------------------------
// k_h2M: H2t[(s*128+t)][b*512+o] = bf16( sum_c w3dB[s][o][c]*hT[b,t][c] )
// MFMA: M=o 512, N=t 16/block, K=128. Grid (8 tt, 32 s, 4 b) x 4 waves.
// ---------------------------------------------------------------------------
__global__ __launch_bounds__(256) void k_h2M(
    const ushort* __restrict__ hT, const ushort* __restrict__ w3dB,
    ushort* __restrict__ h2t)
{
    int tt = blockIdx.x, s = blockIdx.y, b = blockIdx.z;
    int wv = threadIdx.x >> 6, l = threadIdx.x & 63;
    int l15 = l & 15, g = l >> 4;
    int wvoff = wv * 128;

    f32x4 acc[8];
#pragma unroll
    for (int m = 0; m < 8; ++m) acc[m] = (f32x4){0.f, 0.f, 0.f, 0.f};

    const ushort* bbase = hT + (size_t)(b * 128 + tt * 16 + l15) * 128 + g * 8;
    const ushort* abase = w3dB + ((size_t)(s * 512 + wvoff + l15)) * 128 + g * 8;

#pragma unroll
    for (int k0 = 0; k0 < 128; k0 += 32) {
        bf16x8 bv = *(const bf16x8*)(bbase + k0);
#pragma unroll
        for (int m = 0; m < 8; ++m) {
            bf16x8 av = *(const bf16x8*)(abase + (size_t)(m * 16) * 128 + k0);
            acc[m] = __builtin_amdgcn_mfma_f32_16x16x32_bf16(av, bv, acc[m], 0, 0, 0);
        }
    }

    int tglob = tt * 16 + l15;
    ushort* ob = h2t + (size_t)(s * 128 + tglob) * 2048 + b * 512;
#pragma unroll
    for (int m = 0; m < 8; ++m) {
        int o = wvoff + m * 16 + g * 4;
        uint2 pk;
        pk.x = (uint32)f2bf(acc[m][0]) | ((uint32)f2bf(acc[m][1]) << 16);
        pk.y = (uint32)f2bf(acc[m][2]) | ((uint32)f2bf(acc[m][3]) << 16);
        *(uint2*)(ob + o) = pk;
    }
}

// ---------------------------------------------------------------------------
// k_bm (proven, untouched): cm2[ij, bo] = relu(b3d + sum w*H2t[st,bo])
// ---------------------------------------------------------------------------
__global__ __launch_bounds__(64) void k_bm(
    const ushort* __restrict__ h2t, const int2* __restrict__ taps,
    const uint32* __restrict__ cntij, const float* __restrict__ b3d,
    ushort* __restrict__ cm2)
{
    __shared__ int2 tl[4 * 192];        // 6,144 B
    int boT = blockIdx.x;
    int i = blockIdx.y >> 4, oc = blockIdx.y & 15;
    int tid = threadIdx.x;
    int bo0 = boT * 256 + tid * 4;
    const char* hb = (const char*)h2t + (size_t)bo0 * 2;
    float4 bias = *(const float4*)(b3d + (bo0 & 511));

    for (int jc = 0; jc < 2; ++jc) {
        int j0 = oc * 8 + jc * 4;
        int ij0 = i * 128 + j0;
        int cnts[4];
#pragma unroll
        for (int c = 0; c < 4; ++c) cnts[c] = (int)cntij[ij0 + c];
        __syncthreads();   // previous chunk's readers done before tl overwrite
        for (int n = tid; n < 768; n += 64) {
            int c = n / 192, k = n - c * 192;
            if (k < cnts[c]) tl[n] = taps[(size_t)(ij0 + c) * 192 + k];
        }
        __syncthreads();
#pragma unroll 1
        for (int c = 0; c < 4; ++c) {
            int cnt = cnts[c];
            const int2* tp = &tl[c * 192];
            float a0 = 0.f, a1 = 0.f, a2 = 0.f, a3 = 0.f;
#pragma unroll 8
            for (int k = 0; k < cnt; ++k) {
                int2 r = tp[k];
                uint2 hv = *(const uint2*)(hb + (uint32)r.y);
                float w = __int_as_float(r.x);
                a0 += w * __uint_as_float(hv.x << 16);
                a1 += w * __uint_as_float(hv.x & 0xffff0000u);
                a2 += w * __uint_as_float(hv.y << 16);
                a3 += w * __uint_as_float(hv.y & 0xffff0000u);
            }
            float v0 = fmaxf(a0 + bias.x, 0.f);
            float v1 = fmaxf(a1 + bias.y, 0.f);
            float v2 = fmaxf(a2 + bias.z, 0.f);
            float v3 = fmaxf(a3 + bias.w, 0.f);
            uint64_t pr = (uint64_t)((uint32)f2bf(v0) | ((uint32)f2bf(v1) << 16))
                        | ((uint64_t)((uint32)f2bf(v2) | ((uint32)f2bf(v3) << 16)) << 32);
            __builtin_nontemporal_store(pr, (uint64_t*)(cm2 + (size_t)(ij0 + c) * 2048 + bo0));
        }
    }
}

// ---------------------------------------------------------------------------
// conv-a via MFMA: p1b[b][ij][c] = bf16(relu(ba[c] + sum_o waB[c,o]*cm2[ij,b*512+o]))
// ---------------------------------------------------------------------------
__global__ __launch_bounds__(256) void k_convaM(
    const ushort* __restrict__ cm2, const ushort* __restrict__ waB,
    const float* __restrict__ ba, ushort* __restrict__ p1b)
{
    int b = blockIdx.y;
    int wv = threadIdx.x >> 6, l = threadIdx.x & 63;
    int ij0 = blockIdx.x * 64 + wv * 16;
    int l15 = l & 15, g = l >> 4;

    f32x4 acc[8];
#pragma unroll
    for (int m = 0; m < 8; ++m) acc[m] = (f32x4){0.f, 0.f, 0.f, 0.f};

    const ushort* bbase = cm2 + (size_t)(ij0 + l15) * 2048 + b * 512 + g * 8;
    const ushort* abase = waB + (size_t)l15 * 512 + g * 8;

#pragma unroll 2
    for (int o0 = 0; o0 < 512; o0 += 32) {
        bf16x8 bv = *(const bf16x8*)(bbase + o0);
#pragma unroll
        for (int m = 0; m < 8; ++m) {
            bf16x8 av = *(const bf16x8*)(abase + (size_t)(m * 16) * 512 + o0);
            acc[m] = __builtin_amdgcn_mfma_f32_16x16x32_bf16(av, bv, acc[m], 0, 0, 0);
        }
    }

    int ij = ij0 + l15;
    ushort* ob = p1b + ((size_t)(b * 16384 + ij)) * 128;
#pragma unroll
    for (int m = 0; m < 8; ++m) {
        int c = m * 16 + g * 4;
        float v0 = fmaxf(acc[m][0] + ba[c], 0.f);
        float v1 = fmaxf(acc[m][1] + ba[c + 1], 0.f);
        float v2 = fmaxf(acc[m][2] + ba[c + 2], 0.f);
        float v3 = fmaxf(acc[m][3] + ba[c + 3], 0.f);
        uint2 pk;
        pk.x = (uint32)f2bf(v0) | ((uint32)f2bf(v1) << 16);
        pk.y = (uint32)f2bf(v2) | ((uint32)f2bf(v3) << 16);
        *(uint2*)(ob + c) = pk;
    }
}

// ---------------------------------------------------------------------------
// 3x3 conv via MFMA (implicit GEMM over 9 shifted taps).
// MODE 1: bf16 out [b][ij][64]. MODE 2: fused final 1x1(64->4)+sigmoid.
// ---------------------------------------------------------------------------
template <int CIN, int MODE>
__global__ __launch_bounds__(256) void k_conv3x3M(
    const ushort* __restrict__ inB, const ushort* __restrict__ wB,
    const float* __restrict__ bias, void* __restrict__ outp,
    const float* __restrict__ wd, const float* __restrict__ bd)
{
    int b = blockIdx.y;
    int wv = threadIdx.x >> 6, l = threadIdx.x & 63;
    int l15 = l & 15, g = l >> 4;
    int tile = blockIdx.x;                 // 0..255
    int i = tile >> 1;
    int j = (tile & 1) * 64 + wv * 16 + l15;
    const ushort* inb = inB + (size_t)b * 16384 * CIN;

    f32x4 acc[4];
#pragma unroll
    for (int m = 0; m < 4; ++m) acc[m] = (f32x4){0.f, 0.f, 0.f, 0.f};

#pragma unroll
    for (int ky = 0; ky < 3; ++ky) {
        int ii = i + ky - 1;
        if (ii < 0 || ii >= 128) continue;      // uniform per block
#pragma unroll
        for (int kx = 0; kx < 3; ++kx) {
            int jv = j + kx - 1;
            bool ok = (jv >= 0) && (jv < 128);  // per-lane
            const ushort* bp = inb + (size_t)(ii * 128 + jv) * CIN + g * 8;
            const ushort* ap = wB + (size_t)((ky * 3 + kx) * 64 + l15) * CIN + g * 8;
#pragma unroll
            for (int o0 = 0; o0 < CIN; o0 += 32) {
                bf16x8 bv;
                if (ok) bv = *(const bf16x8*)(bp + o0);
                else    bv = (bf16x8){0, 0, 0, 0, 0, 0, 0, 0};
#pragma unroll
                for (int m = 0; m < 4; ++m) {
                    bf16x8 av = *(const bf16x8*)(ap + (size_t)(m * 16) * CIN + o0);
                    acc[m] = __builtin_amdgcn_mfma_f32_16x16x32_bf16(av, bv, acc[m], 0, 0, 0);
                }
            }
        }
    }

    int ij = i * 128 + j;
    if (MODE == 1) {
        ushort* ob = (ushort*)outp + ((size_t)(b * 16384 + ij)) * 64;
#pragma unroll
        for (int m = 0; m < 4; ++m) {
            int c = m * 16 + g * 4;
            float v0 = fmaxf(acc[m][0] + bias[c], 0.f);
            float v1 = fmaxf(acc[m][1] + bias[c + 1], 0.f);
            float v2 = fmaxf(acc[m][2] + bias[c + 2], 0.f);
            float v3 = fmaxf(acc[m][3] + bias[c + 3], 0.f);
            uint2 pk;
            pk.x = (uint32)f2bf(v0) | ((uint32)f2bf(v1) << 16);
            pk.y = (uint32)f2bf(v2) | ((uint32)f2bf(v3) << 16);
            *(uint2*)(ob + c) = pk;
        }
    } else {
        // MODE 2: relu(conv_c) then fused 1x1(64->4) + sigmoid to d_out.
        float v[4][4];
#pragma unroll
        for (int m = 0; m < 4; ++m) {
            int c = m * 16 + g * 4;
#pragma unroll
            for (int r = 0; r < 4; ++r)
                v[m][r] = fmaxf(acc[m][r] + bias[c + r], 0.f);
        }
        float s[4];
#pragma unroll
        for (int oc = 0; oc < 4; ++oc) {
            float t = 0.0f;
#pragma unroll
            for (int m = 0; m < 4; ++m) {
                int c = m * 16 + g * 4;
#pragma unroll
                for (int r = 0; r < 4; ++r)
                    t += wd[oc * 64 + c + r] * v[m][r];
            }
            t += __shfl_xor(t, 16);
            t += __shfl_xor(t, 32);
            s[oc] = t;
        }
        if (g == 0) {
            float* od = (float*)outp;
            od[1536 + (size_t)(b * 2 + 0) * 16384 + ij] = sigmoidf(s[2] + bd[2]);  // iou ch0
            od[1536 + (size_t)(b * 2 + 1) * 16384 + ij] = sigmoidf(s[3] + bd[3]);  // iou ch1
            od[132608 + (size_t)b * 16384 + ij] = sigmoidf(s[0] + bd[0]);          // prop_start
            od[198144 + (size_t)b * 16384 + ij] = sigmoidf(s[1] + bd[1]);          // prop_end
        }
    }
}

// ---------------------------------------------------------------------------
extern "C" void kernel_launch(void* const* d_in, const int* in_sizes, int n_in,
                              void* d_out, int out_size, void* d_ws, size_t ws_size,
                              hipStream_t stream)
{
    const float* x   = (const float*)d_in[0];
    const float* w1  = (const float*)d_in[1];
    const float* b1  = (const float*)d_in[2];
    const float* w2  = (const float*)d_in[3];
    const float* b2  = (const float*)d_in[4];
    const float* w3  = (const float*)d_in[5];
    const float* b3  = (const float*)d_in[6];
    const float* w3d = (const float*)d_in[7];
    const float* b3d = (const float*)d_in[8];
    const float* wa  = (const float*)d_in[9];
    const float* ba  = (const float*)d_in[10];
    const float* wb  = (const float*)d_in[11];
    const float* bb  = (const float*)d_in[12];
    const float* wc  = (const float*)d_in[13];
    const float* bc  = (const float*)d_in[14];
    const float* wd  = (const float*)d_in[15];
    const float* bd  = (const float*)d_in[16];
    const float* sm  = (const float*)d_in[17];
    float* outp = (float*)d_out;
    char* ws = (char*)d_ws;

    // workspace layout (with aliasing; peak ~127.3 MB)
    ushort* hT    = (ushort*)(ws + 1048576);       //    131,072 B (persistent till h2M)
    ushort* h2t   = (ushort*)(ws + 1310720);       // 16,777,216 B
    uint32* ecnt  = (uint32*)(ws + 18087936);      //  2,097,152 B
    uint8_t* et   = (uint8_t*)(ws + 20185088);     //  4,194,304 B
    float*  ewf   = (float*)(ws + 24379392);       // 16,777,216 B (e1 out; dead after e2)
    uint32* cntij = (uint32*)(ws + 41156608);      //     65,536 B
    int2*   taps  = (int2*)(ws + 41222144);        // 25,165,824 B
    ushort* cm2   = (ushort*)(ws + 66387968);      // 67,108,864 B  [ij][bo]
    ushort* p1b   = (ushort*)(ws + 1310720);       // 16,777,216 B (aliases h2t; dead then)
    ushort* p2b   = (ushort*)(ws + 41222144);      //  8,388,608 B (aliases taps; dead then)
    // transients in the ewf zone (24,379,392..41,156,608):
    //   prepA outputs (dead before e1):
    ushort* xcolB = (ushort*)(ws + 24379392);      //    622,592 B
    ushort* w1bB  = (ushort*)(ws + 25001984);      //    622,592 B
    ushort* h1t   = (ushort*)(ws + 25624576);      //    524,288 B
    ushort* w2bB  = (ushort*)(ws + 26148864);      //    393,216 B
    //   prep2 outputs (written after e2):
    ushort* w3dB  = (ushort*)(ws + 24379392);      //  4,194,304 B
    ushort* wbB   = (ushort*)(ws + 34865152);      //    147,456 B
    ushort* wcB   = (ushort*)(ws + 35012608);      //     73,728 B
    ushort* waB   = (ushort*)(ws + 35307520);      //    131,072 B (ends < cntij)

    dim3 blk(256);
    k_prepA<<<3200, blk, 0, stream>>>(w1, w1bB, x, xcolB, w2, w2bB);
    k_gemm1<<<dim3(8, 4), blk, 0, stream>>>(xcolB, w1bB, b1, h1t);
    k_conv1k3<<<32, blk, 0, stream>>>(h1t, w2bB, b2, hT);
    k_x4<<<1, 512, 0, stream>>>(hT, w3, b3, outp);
    k_e1<<<2048, blk, 0, stream>>>(sm, ecnt, et, ewf);
    k_e2<<<8192, 64, 0, stream>>>(ecnt, et, ewf, cntij, taps);
    k_prep2<<<1200, blk, 0, stream>>>(w3d, w3dB, wb, wbB, wc, wcB, wa, waB);
    k_h2M<<<dim3(8, 32, 4), blk, 0, stream>>>(hT, w3dB, h2t);
    k_bm<<<dim3(8, 2048), dim3(64), 0, stream>>>(h2t, taps, cntij, b3d, cm2);
    k_convaM<<<dim3(256, 4), blk, 0, stream>>>(cm2, waB, ba, p1b);
    k_conv3x3M<128, 1><<<dim3(256, 4), blk, 0, stream>>>(p1b, wbB, bb, (void*)p2b, nullptr, nullptr);
    k_conv3x3M<64, 2><<<dim3(256, 4), blk, 0, stream>>>(p2b, wcB, bc, (void*)outp, wd, bd);
}